// Round 10
// baseline (335.547 us; speedup 1.0000x reference)
//
#include <hip/hip_runtime.h>

typedef __attribute__((ext_vector_type(8))) short bf16x8;
typedef __attribute__((ext_vector_type(4))) float f32x4;

#define SZQKV 12582912  // B*N*C = one (q|k|v) output block, elements

__device__ __forceinline__ unsigned short f2bf(float f) {
    unsigned int u = __float_as_uint(f);
    unsigned int r = (u + 0x7FFFu + ((u >> 16) & 1u)) >> 16;
    return (unsigned short)r;
}

#define GLDS16(g, l) __builtin_amdgcn_global_load_lds( \
    (const __attribute__((address_space(1))) unsigned int*)(g), \
    (__attribute__((address_space(3))) unsigned int*)(l), 16, 0, 0)

// ---------------- cast f32 -> bf16 into workspace ----------------
__global__ void cast_all(const float* __restrict__ x,
                         const float* __restrict__ wqkv,
                         const float* __restrict__ wproj,
                         unsigned short* __restrict__ dst) {
    const int T1 = 12582912;       // x
    const int T2 = T1 + 1769472;   // + w_qkv
    const int T3 = T2 + 589824;    // + w_proj
    int stride = gridDim.x * blockDim.x * 4;
    for (int base = (blockIdx.x * blockDim.x + threadIdx.x) * 4; base < T3; base += stride) {
        const float* src; int off;
        if (base < T1)      { src = x;     off = base; }
        else if (base < T2) { src = wqkv;  off = base - T1; }
        else                { src = wproj; off = base - T2; }
        float4 v = *(const float4*)(src + off);
        ushort4 o;
        o.x = f2bf(v.x); o.y = f2bf(v.y); o.z = f2bf(v.z); o.w = f2bf(v.w);
        *(ushort4*)(dst + base) = o;
    }
}

// ---- qkv GEMM: R9 config, INSTRUMENTED with 3 identical internal reps ----
// (measurement round: t_qkv = (total - 174.3)/2; counters become visible in top-5)
__global__ __launch_bounds__(256, 2) void gemm_qkv(const unsigned short* __restrict__ A,
                                                   const unsigned short* __restrict__ Bw,
                                                   float* __restrict__ dout) {
    __shared__ unsigned char lds8[73728];
    const int t = threadIdx.x;
    const int lane = t & 63;
    const int w = t >> 6;
    const int wm = w >> 1, wn = w & 1;   // 2m x 2n waves, 128x64 per wave

    const int cpx = gridDim.x >> 3;
    const int orig = blockIdx.x;
    const int wgid = (orig & 7) * cpx + (orig >> 3);
    const int bx = wgid / 18, by = wgid - bx * 18;
    const int m0 = bx * 256, n0 = by * 128;

    const unsigned char* Ab = (const unsigned char*)A;
    const unsigned char* Bb = (const unsigned char*)Bw;

    const int srow = t >> 2;
    const int sc = ((t & 3) ^ (srow & 3)) << 4;
    const size_t aBase = (size_t)(m0 + srow) * 1536 + sc;
    const size_t bBase = (size_t)(n0 + srow) * 1536 + sc;
    const int ldst = t * 16;

    const int rA = wm * 128 + (lane & 15);
    const int rB = wn * 64 + (lane & 15);
    const int xt = (((lane >> 4)) ^ (lane & 3)) << 4;

#define STAGE(kt, bi) do { \
    unsigned char* db_ = lds8 + (bi) * 24576; \
    const size_t ko_ = (size_t)(kt) * 64; \
    GLDS16(Ab + aBase + ko_,          db_ + ldst); \
    GLDS16(Ab + aBase + ko_ + 98304,  db_ + ldst + 4096); \
    GLDS16(Ab + aBase + ko_ + 196608, db_ + ldst + 8192); \
    GLDS16(Ab + aBase + ko_ + 294912, db_ + ldst + 12288); \
    GLDS16(Bb + bBase + ko_,          db_ + 16384 + ldst); \
    GLDS16(Bb + bBase + ko_ + 98304,  db_ + 16384 + ldst + 4096); \
} while (0)

#define LDA4(mb_) do { \
    _Pragma("unroll") \
    for (int mi = 0; mi < 4; ++mi) \
        av[mi] = *(const bf16x8*)(bufA + (rA + (mb_) + mi * 16) * 64 + xt); \
} while (0)

#define MM(rbase_) do { \
    __builtin_amdgcn_s_setprio(1); \
    _Pragma("unroll") \
    for (int mi = 0; mi < 4; ++mi) \
    _Pragma("unroll") \
    for (int ni = 0; ni < 4; ++ni) \
        acc[(rbase_) + mi][ni] = __builtin_amdgcn_mfma_f32_16x16x32_bf16(av[mi], bv[ni], acc[(rbase_) + mi][ni], 0, 0, 0); \
    __builtin_amdgcn_s_setprio(0); \
} while (0)

    for (int rep = 0; rep < 3; ++rep) {
        f32x4 acc[8][4] = {};

        STAGE(0, 0);
        STAGE(1, 1);
        int bi = 0;
        for (int kt = 0; kt < 24; ++kt) {
            if (kt < 22) {
                int si = bi + 2; if (si >= 3) si -= 3;
                STAGE(kt + 2, si);
                asm volatile("s_waitcnt vmcnt(12)" ::: "memory");
            } else if (kt == 22) {
                asm volatile("s_waitcnt vmcnt(6)" ::: "memory");
            } else {
                asm volatile("s_waitcnt vmcnt(0)" ::: "memory");
            }
            __builtin_amdgcn_s_barrier();
            asm volatile("" ::: "memory");
            const unsigned char* bufA = lds8 + bi * 24576;
            const unsigned char* bufB = bufA + 16384;
            bf16x8 av[4], bv[4];
#pragma unroll
            for (int ni = 0; ni < 4; ++ni)
                bv[ni] = *(const bf16x8*)(bufB + (rB + ni * 16) * 64 + xt);
            LDA4(0);  MM(0);
            LDA4(64); MM(4);
            asm volatile("s_waitcnt lgkmcnt(0)" ::: "memory");
            __builtin_amdgcn_s_barrier();
            asm volatile("" ::: "memory");
            ++bi; if (bi == 3) bi = 0;
        }

        // direct-scatter epilogue: f32x4 = 4 consecutive n per store
        const int crow = (lane >> 4) * 4;
        const int ccol = lane & 15;
        const int b = m0 >> 12;
        const int n_base = m0 & 4095;
#pragma unroll
        for (int mi = 0; mi < 8; ++mi) {
            int n = n_base + wm * 128 + mi * 16 + crow;
#pragma unroll
            for (int ni = 0; ni < 4; ++ni) {
                int o = n0 + wn * 64 + ni * 16 + ccol;  // column in [0,2304)
                int sel = o / 768;                      // 0=q 1=k 2=v
                int rem = o - sel * 768;                // dil*256 + c'
                float* dst = dout + (size_t)(3 - sel) * SZQKV
                           + ((size_t)((rem >> 8) * 4 + b) * 256 + (rem & 255)) * 4096 + n;
                *(f32x4*)dst = acc[mi][ni];
            }
        }
        // make sure stores of this rep are issued before next rep reuses LDS/pipeline
        __builtin_amdgcn_s_barrier();
        asm volatile("" ::: "memory");
    }
#undef STAGE
#undef LDA4
#undef MM
}

// ---------------- proj GEMM: 128x128 tile, BK=32, 4 waves, ring-3 dist-2, 3 blk/CU ----------------
__global__ __launch_bounds__(256, 3) void gemm_proj128(const unsigned short* __restrict__ A,
                                                       const unsigned short* __restrict__ Bw,
                                                       const float* __restrict__ bias,
                                                       float* __restrict__ dout) {
    __shared__ unsigned char lds8[49152];
    const int t = threadIdx.x;
    const int lane = t & 63;
    const int w = t >> 6;                 // 0..3
    const int wm = w >> 1, wn = w & 1;    // 2m x 2n waves, 64x64 per wave

    const int cpx = gridDim.x >> 3;       // grid 768 % 8 == 0
    const int orig = blockIdx.x;
    const int wgid = (orig & 7) * cpx + (orig >> 3);
    const int bx = wgid / 6, by = wgid - bx * 6;
    const int m0 = bx * 128, n0 = by * 128;

    const unsigned char* Ab = (const unsigned char*)A;
    const unsigned char* Bb = (const unsigned char*)Bw;

    const int srow = t >> 2;
    const int sc = ((t & 3) ^ (srow & 3)) << 4;
    const size_t aBase = (size_t)(m0 + srow) * 1536 + sc;
    const size_t bBase = (size_t)(n0 + srow) * 1536 + sc;
    const int ldst = t * 16;

    const int rA = wm * 64 + (lane & 15);
    const int rB = wn * 64 + (lane & 15);
    const int xt = (((lane >> 4)) ^ (lane & 3)) << 4;

    f32x4 acc[4][4] = {};

#define STAGE(kt, bi) do { \
    unsigned char* db_ = lds8 + (bi) * 16384; \
    const size_t ko_ = (size_t)(kt) * 64; \
    GLDS16(Ab + aBase + ko_,         db_ + ldst); \
    GLDS16(Ab + aBase + ko_ + 98304, db_ + ldst + 4096); \
    GLDS16(Bb + bBase + ko_,         db_ + 8192 + ldst); \
    GLDS16(Bb + bBase + ko_ + 98304, db_ + 8192 + ldst + 4096); \
} while (0)

    STAGE(0, 0);
    STAGE(1, 1);
    int bi = 0;
    for (int kt = 0; kt < 24; ++kt) {
        if (kt < 22) {
            int si = bi + 2; if (si >= 3) si -= 3;
            STAGE(kt + 2, si);
            asm volatile("s_waitcnt vmcnt(8)" ::: "memory");   // tile kt's 4 loads done
        } else if (kt == 22) {
            asm volatile("s_waitcnt vmcnt(4)" ::: "memory");
        } else {
            asm volatile("s_waitcnt vmcnt(0)" ::: "memory");
        }
        __builtin_amdgcn_s_barrier();
        asm volatile("" ::: "memory");
        const unsigned char* bufA = lds8 + bi * 16384;
        const unsigned char* bufB = bufA + 8192;
        bf16x8 av[4], bv[4];
#pragma unroll
        for (int mi = 0; mi < 4; ++mi)
            av[mi] = *(const bf16x8*)(bufA + (rA + mi * 16) * 64 + xt);
#pragma unroll
        for (int ni = 0; ni < 4; ++ni)
            bv[ni] = *(const bf16x8*)(bufB + (rB + ni * 16) * 64 + xt);
#pragma unroll
        for (int mi = 0; mi < 4; ++mi)
#pragma unroll
            for (int ni = 0; ni < 4; ++ni)
                acc[mi][ni] = __builtin_amdgcn_mfma_f32_16x16x32_bf16(av[mi], bv[ni], acc[mi][ni], 0, 0, 0);
        asm volatile("s_waitcnt lgkmcnt(0)" ::: "memory");
        __builtin_amdgcn_s_barrier();
        asm volatile("" ::: "memory");
        ++bi; if (bi == 3) bi = 0;
    }
#undef STAGE

    // epilogue: 2 sweeps of 64(m) x 128(o) f32 (32KB LDS), 512B-contiguous stores + bias
    float* ldsf = (float*)lds8;
    const int ccol = lane & 15;
    const int hi4 = (lane >> 4) * 4;
#pragma unroll
    for (int s = 0; s < 2; ++s) {
        if (wm == s) {
#pragma unroll
            for (int mi = 0; mi < 4; ++mi)
#pragma unroll
                for (int ni = 0; ni < 4; ++ni) {
                    int o = wn * 64 + ni * 16 + ccol;          // 0..127
                    int m2b = mi * 16 + hi4;                   // 0..63 (+r)
#pragma unroll
                    for (int r = 0; r < 4; ++r)
                        ldsf[(m2b + r) * 128 + (o ^ (((m2b + r) & 7) << 2))] = acc[mi][ni][r];
                }
        }
        asm volatile("s_waitcnt lgkmcnt(0)" ::: "memory");
        __builtin_amdgcn_s_barrier();
        asm volatile("" ::: "memory");
#pragma unroll
        for (int it = 0; it < 8; ++it) {
            int idx = it * 256 + t;                            // 0..2047
            int row = idx >> 5;                                // 0..63
            int c4 = (idx & 31) * 4;                           // 0..124
            f32x4 v = *(const f32x4*)&ldsf[row * 128 + (c4 ^ ((row & 7) << 2))];
            f32x4 b4 = *(const f32x4*)(bias + n0 + c4);
            v = v + b4;
            float* dst = dout + (size_t)(m0 + s * 64 + row) * 768 + n0 + c4;
            *(f32x4*)dst = v;
        }
        if (s == 0) {
            __builtin_amdgcn_s_barrier();
            asm volatile("" ::: "memory");
        }
    }
}

// ---------------- attention: read q/k/v f32 from d_out, write bf16 [b][n][c] ----------------
__global__ __launch_bounds__(256) void attn_kernel(const float* __restrict__ qkv,
                                                   unsigned short* __restrict__ attnbf) {
    const int chunk = blockIdx.x;  // 64 chunks of 64 n
    const int dil_i = blockIdx.y;  // 0..2
    const int b     = blockIdx.z;  // 0..3
    const int dil   = dil_i + 1;
    const int t  = threadIdx.x;
    const int h  = t >> 6;         // wave = head
    const int nl = t & 63;
    const int n  = chunk * 64 + nl;

    const size_t gb = (size_t)(dil_i * 4 + b) * 256 * 4096;
    const float* Q = qkv + (size_t)3 * SZQKV + gb;
    const float* K = qkv + (size_t)2 * SZQKV + gb;
    const float* V = qkv + (size_t)1 * SZQKV + gb;

    const int nm = n - dil, np = n + dil;
    const bool vm = (nm >= 0), vp = (np < 4096);
    const int nmc = vm ? nm : 0, npc = vp ? np : 4095;

    float s0 = 0.f, s1 = 0.f, s2 = 0.f;
    {
        const float* qrow = Q + (size_t)h * 64 * 4096;
        const float* krow = K + (size_t)h * 64 * 4096;
        for (int d = 0; d < 64; ++d) {
            float q = qrow[n];
            s0 += q * krow[nmc];
            s1 += q * krow[n];
            s2 += q * krow[npc];
            qrow += 4096; krow += 4096;
        }
    }
    s0 = vm ? s0 * 0.125f : 0.f;   // padded K-column -> exact 0 score (matches ref)
    s1 *= 0.125f;
    s2 = vp ? s2 * 0.125f : 0.f;
    float mx = fmaxf(0.f, fmaxf(s0, fmaxf(s1, s2)));
    float e0 = __expf(s0 - mx), e1 = __expf(s1 - mx), e2 = __expf(s2 - mx);
    // softmax over 9 slots: 6 structural zeros contribute 6*exp(-mx)
    float den = e0 + e1 + e2 + 6.f * __expf(-mx);
    float inv = 1.f / den;
    float p0 = vm ? e0 * inv : 0.f;
    float p1 = e1 * inv;
    float p2 = vp ? e2 * inv : 0.f;

    __shared__ unsigned short lout[256][65];  // [c'][n] bf16, padded row
    {
        const float* vrow = V + (size_t)h * 64 * 4096;
        for (int d = 0; d < 64; ++d) {
            float o = p0 * vrow[nmc] + p1 * vrow[n] + p2 * vrow[npc];
            lout[h * 64 + d][nl] = f2bf(o);
            vrow += 4096;
        }
    }
    __syncthreads();

    // write tile transposed: attnbf[(b*4096+n)*768 + dil_i*256 + c], c fastest
#pragma unroll
    for (int i = 0; i < 8; ++i) {
        int linear = i * 256 + t;   // 0..2047
        int nn   = linear >> 5;     // 0..63
        int cblk = linear & 31;     // 0..31 (8 channels each)
        union { unsigned short u[8]; f32x4 v; } tt;
#pragma unroll
        for (int j = 0; j < 8; ++j) tt.u[j] = lout[cblk * 8 + j][nn];
        unsigned short* dst = attnbf + (size_t)(b * 4096 + chunk * 64 + nn) * 768
                            + dil_i * 256 + cblk * 8;
        *(f32x4*)dst = tt.v;
    }
}

extern "C" void kernel_launch(void* const* d_in, const int* in_sizes, int n_in,
                              void* d_out, int out_size, void* d_ws, size_t ws_size,
                              hipStream_t stream) {
    const float* x     = (const float*)d_in[0];
    const float* wqkv  = (const float*)d_in[1];
    const float* wproj = (const float*)d_in[2];
    const float* bproj = (const float*)d_in[3];
    float* out = (float*)d_out;

    unsigned short* xbf     = (unsigned short*)d_ws;          // 12582912
    unsigned short* wqkvbf  = xbf + 12582912;                 // 1769472
    unsigned short* wprojbf = wqkvbf + 1769472;               // 589824
    unsigned short* attnbf  = wprojbf + 589824;               // 12582912

    cast_all<<<2048, 256, 0, stream>>>(x, wqkv, wproj, xbf);

    // qkv: M=16384 (64 m-tiles of 256), Nw=2304 (18 n-tiles of 128) -> 1152 blocks (%8==0)
    gemm_qkv<<<dim3(1152), 256, 0, stream>>>(xbf, wqkvbf, out);

    attn_kernel<<<dim3(64, 3, 4), 256, 0, stream>>>(out, attnbf);

    // proj: M=16384 (128 m-tiles), Nw=768 (6 n-tiles) -> 768 blocks, 3 blk/CU, 1.0 rounds
    gemm_proj128<<<dim3(768), 256, 0, stream>>>(attnbf, wprojbf, bproj, out);
}